// Round 12
// baseline (238.789 us; speedup 1.0000x reference)
//
#include <hip/hip_runtime.h>

#define K_DIM 256
#define OD 128
#define BSH 5                 // 32 rows per bucket
#define BROWS 32
#define BCAP 2048             // entries per bucket region (mean 1024, sd ~32)
#define FILL_THREADS 1024
#define FILL_CHUNK 4096       // 4 edges per thread
#define NB_MAX 2048

typedef __attribute__((ext_vector_type(8))) short short8;
typedef __attribute__((ext_vector_type(4))) float f32x4;

__device__ inline unsigned short f2bf(float f) {
    unsigned u = __float_as_uint(f);
    unsigned r = (u + 0x7fffu + ((u >> 16) & 1u)) >> 16;   // round-to-nearest-even
    return (unsigned short)r;
}

union Frag8 { short8 s; uint4 u; };

// ---------------- init: pack W -> bf16 MFMA B-frag-linear, + bucket cursors ----------------
__global__ __launch_bounds__(256) void init_pack(const float* __restrict__ W,
                                                 uint4* __restrict__ wb,
                                                 int* __restrict__ gcur, int NB) {
    if ((int)blockIdx.x == 16) {           // bucket cursor init (padded: one per 64B line)
        for (int i = threadIdx.x; i < NB; i += 256) gcur[i * 16] = i * BCAP;
        return;
    }
    int t = blockIdx.x * 256 + threadIdx.x;
    if (t >= 8 * 8 * 64) return;
    int l  = t & 63;
    int n  = (t >> 6) & 7;
    int ks = t >> 9;
    int g  = l >> 4;
    int col = 16 * n + (l & 15);
    int kb  = 32 * ks + 4 * g;
    unsigned short e[8];
    #pragma unroll
    for (int j = 0; j < 8; ++j) {
        int k = kb + (j & 3) + 16 * (j >> 2);
        e[j] = f2bf(W[(size_t)k * OD + col]);
    }
    uint4 u;
    u.x = (unsigned)e[0] | ((unsigned)e[1] << 16);
    u.y = (unsigned)e[2] | ((unsigned)e[3] << 16);
    u.z = (unsigned)e[4] | ((unsigned)e[5] << 16);
    u.w = (unsigned)e[6] | ((unsigned)e[7] << 16);
    wb[t] = u;
}

// ---------------- MFMA GEMM: prebp slice-major packed bf16(x @ W) ----------------
// slice s=0..7, j=0..7: prebp[(s*M + row)*8 + j] = bf16(col 8s+j) | bf16(col 8s+j+64)<<16
__global__ __launch_bounds__(256) void gemm_mfma(const float* __restrict__ x,
                                                 const uint4* __restrict__ wb,
                                                 unsigned* __restrict__ prebp, int M) {
    const int t = threadIdx.x;
    const int l = t & 63;
    const int w = t >> 6;
    const int g = l >> 4;
    const int row  = blockIdx.x * 64 + w * 16 + (l & 15);
    const int rowc = row < M ? row : M - 1;
    const float* xp = x + (size_t)rowc * K_DIM + g * 4;

    f32x4 acc[8];
    #pragma unroll
    for (int n = 0; n < 8; ++n) acc[n] = (f32x4){0.f, 0.f, 0.f, 0.f};

    #pragma unroll
    for (int ks = 0; ks < 8; ++ks) {
        float4 xa = *reinterpret_cast<const float4*>(xp + 32 * ks);
        float4 xb = *reinterpret_cast<const float4*>(xp + 32 * ks + 16);
        Frag8 a;
        a.u.x = (unsigned)f2bf(xa.x) | ((unsigned)f2bf(xa.y) << 16);
        a.u.y = (unsigned)f2bf(xa.z) | ((unsigned)f2bf(xa.w) << 16);
        a.u.z = (unsigned)f2bf(xb.x) | ((unsigned)f2bf(xb.y) << 16);
        a.u.w = (unsigned)f2bf(xb.z) | ((unsigned)f2bf(xb.w) << 16);
        const uint4* wp = wb + (size_t)ks * 8 * 64 + l;
        #pragma unroll
        for (int n = 0; n < 8; ++n) {
            Frag8 bfrag;
            bfrag.u = wp[n * 64];
            acc[n] = __builtin_amdgcn_mfma_f32_16x16x32_bf16(a.s, bfrag.s, acc[n], 0, 0, 0);
        }
    }
    const int rbase = blockIdx.x * 64 + w * 16 + g * 4;
    const int c16 = l & 15;
    #pragma unroll
    for (int r = 0; r < 4; ++r) {
        int ro = rbase + r;
        if (ro < M) {
            #pragma unroll
            for (int n = 0; n < 4; ++n) {
                int s = 2 * n + (c16 >> 3);
                int j = c16 & 7;
                prebp[((size_t)s * M + ro) * 8 + j] =
                    (unsigned)f2bf(acc[n][r]) | ((unsigned)f2bf(acc[n + 4][r]) << 16);
            }
        }
    }
}

// ---------------- fill: bucket-grouped edge stream (u32 entry + u8 row) ----------------
// entry = col<<16 | bf16(val). Bucket b region: csr32/crow[b*BCAP ...).
__global__ __launch_bounds__(1024) void fill_bucket(const int* __restrict__ rows,
                                                    const int* __restrict__ cols,
                                                    const float* __restrict__ vals,
                                                    int* __restrict__ gcur,
                                                    unsigned* __restrict__ csr32,
                                                    unsigned char* __restrict__ crow,
                                                    int E, int NB) {
    __shared__ int cnt[NB_MAX];
    __shared__ int base[NB_MAX];
    const int t  = threadIdx.x;
    const int e0 = blockIdx.x * FILL_CHUNK;
    for (int i = t; i < NB; i += FILL_THREADS) cnt[i] = 0;
    __syncthreads();
    int  r[4]; int c[4]; float v[4]; bool ok[4];
    #pragma unroll
    for (int it = 0; it < 4; ++it) {
        int i = e0 + it * FILL_THREADS + t;
        ok[it] = (i < E);
        if (ok[it]) {
            r[it] = rows[i];
            c[it] = cols[i];
            v[it] = vals[i];
            atomicAdd(&cnt[r[it] >> BSH], 1);
        }
    }
    __syncthreads();
    for (int bkt = t; bkt < NB; bkt += FILL_THREADS) {
        int cn = cnt[bkt];
        base[bkt] = cn ? atomicAdd(&gcur[bkt * 16], cn) : 0;   // reserve contiguous run
    }
    __syncthreads();
    #pragma unroll
    for (int it = 0; it < 4; ++it) {
        if (ok[it]) {
            int pos = atomicAdd(&base[r[it] >> BSH], 1);        // LDS int cursor within run
            csr32[pos] = ((unsigned)c[it] << 16) | (unsigned)f2bf(v[it]);
            crow[pos]  = (unsigned char)(r[it] & (BROWS - 1));
        }
    }
}

// ---------------- sort: per-bucket counting sort by row, IN PLACE; emit rbeg/rcnt ----------------
__global__ __launch_bounds__(256) void sort_bucket(const int* __restrict__ gcur,
                                                   unsigned* __restrict__ csr32,
                                                   const unsigned char* __restrict__ crow,
                                                   int* __restrict__ rbeg,
                                                   int* __restrict__ rcnt, int NB) {
    __shared__ unsigned sbuf[BCAP];       // 8 KB
    __shared__ int cnt[BROWS];
    __shared__ int beg[BROWS];
    __shared__ int ofs[BROWS];
    const int t   = threadIdx.x;
    const int bkt = (int)blockIdx.x;
    int nE = gcur[bkt * 16] - bkt * BCAP;
    nE = nE < BCAP ? nE : BCAP;
    unsigned*            ce = csr32 + (size_t)bkt * BCAP;
    const unsigned char* re = crow  + (size_t)bkt * BCAP;

    if (t < BROWS) cnt[t] = 0;
    __syncthreads();
    unsigned er[8]; int rw[8];
    #pragma unroll
    for (int k = 0; k < 8; ++k) {
        int i = t + k * 256;
        if (i < nE) {
            er[k] = ce[i];
            rw[k] = (int)re[i];
            atomicAdd(&cnt[rw[k]], 1);
        } else rw[k] = -1;
    }
    __syncthreads();
    if (t < 64) {
        int c  = (t < BROWS) ? cnt[t] : 0;
        int sc = c;
        #pragma unroll
        for (int o = 1; o < 32; o <<= 1) {
            int u = __shfl_up(sc, o, 64);
            if ((t & 63) >= o) sc += u;
        }
        if (t < BROWS) { beg[t] = sc - c; ofs[t] = sc - c; }
    }
    __syncthreads();
    #pragma unroll
    for (int k = 0; k < 8; ++k) {
        if (rw[k] >= 0) {
            int pos = atomicAdd(&ofs[rw[k]], 1);
            sbuf[pos] = er[k];
        }
    }
    __syncthreads();
    #pragma unroll
    for (int k = 0; k < 8; ++k) {
        int i = t + k * 256;
        if (i < nE) ce[i] = sbuf[i];                      // sorted, coalesced write-back
    }
    if (t < BROWS) {
        rbeg[bkt * BROWS + t] = beg[t];
        rcnt[bkt * BROWS + t] = cnt[t];
    }
}

// ---------------- gather: block=(bucket, slice); slice pinned to XCD via blockIdx%8 ----------------
// Slice s = 16 cols {8s..8s+7} ∪ {8s+64..8s+71} (1.6 MB, L2-resident per XCD).
// 8 lanes/edge -> 8 edges per wave step; zero LDS; shfl-reduce per row.
__global__ __launch_bounds__(256) void gather_s(const int* __restrict__ rbeg,
                                                const int* __restrict__ rcnt,
                                                const unsigned* __restrict__ csr_s,
                                                const unsigned* __restrict__ prebp,
                                                const float* __restrict__ b,
                                                float* __restrict__ out, int M, int NB) {
    const int s   = (int)blockIdx.x & 7;
    const int bkt = (int)blockIdx.x >> 3;
    if (bkt >= NB) return;
    const int t = threadIdx.x, l = t & 63, w = t >> 6;
    const int g8 = l >> 3, j = l & 7;
    const unsigned* sbase = csr_s + (size_t)bkt * BCAP;
    const unsigned* qbase = prebp + (size_t)s * M * 8 + j;
    const float bv0 = b[8 * s + j];
    const float bv1 = b[8 * s + j + 64];
    #pragma unroll 1
    for (int q = 0; q < 8; ++q) {
        const int rr = w + 4 * q;
        const int r  = (bkt << BSH) + rr;
        if (r >= M) continue;
        const int beg = __builtin_nontemporal_load(rbeg + bkt * BROWS + rr);
        const int cn  = __builtin_nontemporal_load(rcnt + bkt * BROWS + rr);
        const int end = beg + cn;
        float a0 = 0.f, a1 = 0.f;
        for (int p0 = beg; p0 < end; p0 += 16) {          // 2 x 8-edge chains per iter
            int iA = p0 + g8, iB = p0 + 8 + g8;
            unsigned eA = (iA < end) ? sbase[iA] : 0u;    // e=0 -> val 0 -> no-op
            unsigned eB = (iB < end) ? sbase[iB] : 0u;
            unsigned pA = qbase[(size_t)((eA >> 16) * 8u)];
            unsigned pB = qbase[(size_t)((eB >> 16) * 8u)];
            float vA = __uint_as_float(eA << 16);
            float vB = __uint_as_float(eB << 16);
            a0 = fmaf(vA, __uint_as_float(pA << 16), a0);
            a1 = fmaf(vA, __uint_as_float(pA & 0xffff0000u), a1);
            a0 = fmaf(vB, __uint_as_float(pB << 16), a0);
            a1 = fmaf(vB, __uint_as_float(pB & 0xffff0000u), a1);
        }
        a0 += __shfl_xor(a0, 8, 64); a0 += __shfl_xor(a0, 16, 64); a0 += __shfl_xor(a0, 32, 64);
        a1 += __shfl_xor(a1, 8, 64); a1 += __shfl_xor(a1, 16, 64); a1 += __shfl_xor(a1, 32, 64);
        if (g8 == 0) {
            __builtin_nontemporal_store(fmaxf(a0 + bv0, 0.f),
                                        out + (size_t)r * OD + 8 * s + j);
            __builtin_nontemporal_store(fmaxf(a1 + bv1, 0.f),
                                        out + (size_t)r * OD + 8 * s + j + 64);
        }
    }
}

// ---------------- fallback (tiny ws): atomic scatter over slice-major prebp ----------------
__global__ __launch_bounds__(256) void spmm_scatter(const int* __restrict__ rows,
                                                    const int* __restrict__ cols,
                                                    const float* __restrict__ vals,
                                                    const unsigned* __restrict__ prebp,
                                                    float* __restrict__ out, int E, int M) {
    const int e    = (int)((blockIdx.x * 256u + threadIdx.x) >> 6);
    const int lane = threadIdx.x & 63;
    if (e >= E) return;
    const int   r = rows[e];
    const int   c = cols[e];
    const float v = vals[e];
    const int s = lane >> 3, j = lane & 7;
    unsigned p = prebp[((size_t)s * M + c) * 8 + j];
    float* o = out + (size_t)r * OD;
    unsafeAtomicAdd(o + lane,      v * __uint_as_float(p << 16));
    unsafeAtomicAdd(o + lane + 64, v * __uint_as_float(p & 0xffff0000u));
}

__global__ __launch_bounds__(256) void bias_relu(float* __restrict__ out,
                                                 const float* __restrict__ b, int n4) {
    int i = blockIdx.x * 256 + threadIdx.x;
    if (i >= n4) return;
    float4 v = reinterpret_cast<float4*>(out)[i];
    int c = (i & ((OD / 4) - 1)) << 2;
    float4 bv = *reinterpret_cast<const float4*>(b + c);
    v.x = fmaxf(v.x + bv.x, 0.f);
    v.y = fmaxf(v.y + bv.y, 0.f);
    v.z = fmaxf(v.z + bv.z, 0.f);
    v.w = fmaxf(v.w + bv.w, 0.f);
    reinterpret_cast<float4*>(out)[i] = v;
}

extern "C" void kernel_launch(void* const* d_in, const int* in_sizes, int n_in,
                              void* d_out, int out_size, void* d_ws, size_t ws_size,
                              hipStream_t stream) {
    const float* x     = (const float*)d_in[0];
    const int*   erows = (const int*)d_in[1];
    const int*   ecols = (const int*)d_in[2];
    const float* evals = (const float*)d_in[3];
    const float* W     = (const float*)d_in[4];
    const float* b     = (const float*)d_in[5];
    float*       out   = (float*)d_out;

    const int M  = in_sizes[0] / K_DIM;          // 50000 nodes
    const int E  = in_sizes[1];                  // 1.6M edges
    const int NB = (M + BROWS - 1) >> BSH;       // 1563 buckets

    // workspace layout (16B-aligned)
    char* ws = (char*)d_ws;
    size_t off = 0;
    auto alloc = [&](size_t bytes) { char* p = ws + off; off = (off + bytes + 15) & ~(size_t)15; return p; };
    unsigned*      prebp = (unsigned*)alloc((size_t)M * 64 * sizeof(unsigned));    // 12.8 MB
    uint4*         wb    = (uint4*)alloc((size_t)8 * 8 * 64 * sizeof(uint4));      // 64 KB
    int*           gcur  = (int*)  alloc((size_t)NB * 16 * sizeof(int));           // padded cursors
    unsigned*      csr32 = (unsigned*)alloc((size_t)NB * BCAP * sizeof(unsigned)); // 12.8 MB
    unsigned char* crow  = (unsigned char*)alloc((size_t)NB * BCAP);               // 3.2 MB
    int*           rbeg  = (int*)  alloc((size_t)NB * BROWS * sizeof(int));        // 200 KB
    int*           rcnt  = (int*)  alloc((size_t)NB * BROWS * sizeof(int));        // 200 KB
    const bool bucket_ok = (off <= ws_size) && (NB <= NB_MAX) && (M <= 65536);

    const int nGemm = (M + 63) / 64;

    if (bucket_ok) {
        init_pack<<<17, 256, 0, stream>>>(W, wb, gcur, NB);
        gemm_mfma<<<nGemm, 256, 0, stream>>>(x, wb, prebp, M);
        fill_bucket<<<(E + FILL_CHUNK - 1) / FILL_CHUNK, FILL_THREADS, 0, stream>>>(
            erows, ecols, evals, gcur, csr32, crow, E, NB);
        sort_bucket<<<NB, 256, 0, stream>>>(gcur, csr32, crow, rbeg, rcnt, NB);
        gather_s<<<8 * NB, 256, 0, stream>>>(rbeg, rcnt, csr32, prebp, b, out, M, NB);
    } else {
        init_pack<<<16, 256, 0, stream>>>(W, wb, gcur, 0);
        gemm_mfma<<<nGemm, 256, 0, stream>>>(x, wb, prebp, M);
        hipMemsetAsync(d_out, 0, (size_t)out_size * sizeof(float), stream);
        spmm_scatter<<<(E + 3) / 4, 256, 0, stream>>>(erows, ecols, evals, prebp, out, E, M);
        bias_relu<<<(out_size / 4 + 255) / 256, 256, 0, stream>>>(out, b, out_size / 4);
    }
}

// Round 13
// 163.787 us; speedup vs baseline: 1.4579x; 1.4579x over previous
//
#include <hip/hip_runtime.h>

#define K_DIM 256
#define OD 128
#define BSH 5                 // 32 rows per bucket
#define BROWS 32
#define BCAP 2048             // entries per bucket region (mean 1024, sd ~32)
#define FILL_THREADS 1024
#define FILL_CHUNK 4096       // 4 edges per thread
#define NB_MAX 2048

typedef __attribute__((ext_vector_type(8))) short short8;
typedef __attribute__((ext_vector_type(4))) float f32x4;

__device__ inline unsigned short f2bf(float f) {
    unsigned u = __float_as_uint(f);
    unsigned r = (u + 0x7fffu + ((u >> 16) & 1u)) >> 16;   // round-to-nearest-even
    return (unsigned short)r;
}

union Frag8 { short8 s; uint4 u; };

// ---------------- init: pack W -> bf16 MFMA B-frag-linear, + bucket cursors ----------------
__global__ __launch_bounds__(256) void init_pack(const float* __restrict__ W,
                                                 uint4* __restrict__ wb,
                                                 int* __restrict__ gcur, int NB) {
    if ((int)blockIdx.x == 16) {           // bucket cursor init (padded: one per 64B line)
        for (int i = threadIdx.x; i < NB; i += 256) gcur[i * 16] = i * BCAP;
        return;
    }
    int t = blockIdx.x * 256 + threadIdx.x;
    if (t >= 8 * 8 * 64) return;
    int l  = t & 63;
    int n  = (t >> 6) & 7;
    int ks = t >> 9;
    int g  = l >> 4;
    int col = 16 * n + (l & 15);
    int kb  = 32 * ks + 4 * g;
    unsigned short e[8];
    #pragma unroll
    for (int j = 0; j < 8; ++j) {
        int k = kb + (j & 3) + 16 * (j >> 2);
        e[j] = f2bf(W[(size_t)k * OD + col]);
    }
    uint4 u;
    u.x = (unsigned)e[0] | ((unsigned)e[1] << 16);
    u.y = (unsigned)e[2] | ((unsigned)e[3] << 16);
    u.z = (unsigned)e[4] | ((unsigned)e[5] << 16);
    u.w = (unsigned)e[6] | ((unsigned)e[7] << 16);
    wb[t] = u;
}

// ---------------- MFMA GEMM: prebp quarter-sliced packed bf16(x @ W) ----------------
// prebp[(q*M + row)*16 + j] = bf16(col 16q+j) | bf16(col 16q+j+64)<<16  (q=0..3, j=0..15)
__global__ __launch_bounds__(256) void gemm_mfma(const float* __restrict__ x,
                                                 const uint4* __restrict__ wb,
                                                 unsigned* __restrict__ prebp, int M) {
    const int t = threadIdx.x;
    const int l = t & 63;
    const int w = t >> 6;
    const int g = l >> 4;
    const int row  = blockIdx.x * 64 + w * 16 + (l & 15);
    const int rowc = row < M ? row : M - 1;
    const float* xp = x + (size_t)rowc * K_DIM + g * 4;

    f32x4 acc[8];
    #pragma unroll
    for (int n = 0; n < 8; ++n) acc[n] = (f32x4){0.f, 0.f, 0.f, 0.f};

    #pragma unroll
    for (int ks = 0; ks < 8; ++ks) {
        float4 xa = *reinterpret_cast<const float4*>(xp + 32 * ks);
        float4 xb = *reinterpret_cast<const float4*>(xp + 32 * ks + 16);
        Frag8 a;
        a.u.x = (unsigned)f2bf(xa.x) | ((unsigned)f2bf(xa.y) << 16);
        a.u.y = (unsigned)f2bf(xa.z) | ((unsigned)f2bf(xa.w) << 16);
        a.u.z = (unsigned)f2bf(xb.x) | ((unsigned)f2bf(xb.y) << 16);
        a.u.w = (unsigned)f2bf(xb.z) | ((unsigned)f2bf(xb.w) << 16);
        const uint4* wp = wb + (size_t)ks * 8 * 64 + l;
        #pragma unroll
        for (int n = 0; n < 8; ++n) {
            Frag8 bfrag;
            bfrag.u = wp[n * 64];
            acc[n] = __builtin_amdgcn_mfma_f32_16x16x32_bf16(a.s, bfrag.s, acc[n], 0, 0, 0);
        }
    }
    const int rbase = blockIdx.x * 64 + w * 16 + g * 4;
    #pragma unroll
    for (int r = 0; r < 4; ++r) {
        int ro = rbase + r;
        if (ro < M) {
            #pragma unroll
            for (int m = 0; m < 4; ++m)
                prebp[((size_t)m * M + ro) * 16 + (l & 15)] =
                    (unsigned)f2bf(acc[m][r]) | ((unsigned)f2bf(acc[m + 4][r]) << 16);
        }
    }
}

// ---------------- fill: bucket-grouped edge stream (u32 entry + u8 row) ----------------
// entry = col<<16 | bf16(val). Bucket b region: csr32/crow[b*BCAP ...).
__global__ __launch_bounds__(1024) void fill_bucket(const int* __restrict__ rows,
                                                    const int* __restrict__ cols,
                                                    const float* __restrict__ vals,
                                                    int* __restrict__ gcur,
                                                    unsigned* __restrict__ csr32,
                                                    unsigned char* __restrict__ crow,
                                                    int E, int NB) {
    __shared__ int cnt[NB_MAX];
    __shared__ int base[NB_MAX];
    const int t  = threadIdx.x;
    const int e0 = blockIdx.x * FILL_CHUNK;
    for (int i = t; i < NB; i += FILL_THREADS) cnt[i] = 0;
    __syncthreads();
    int  r[4]; int c[4]; float v[4]; bool ok[4];
    #pragma unroll
    for (int it = 0; it < 4; ++it) {
        int i = e0 + it * FILL_THREADS + t;
        ok[it] = (i < E);
        if (ok[it]) {
            r[it] = rows[i];
            c[it] = cols[i];
            v[it] = vals[i];
            atomicAdd(&cnt[r[it] >> BSH], 1);
        }
    }
    __syncthreads();
    for (int bkt = t; bkt < NB; bkt += FILL_THREADS) {
        int cn = cnt[bkt];
        base[bkt] = cn ? atomicAdd(&gcur[bkt * 16], cn) : 0;   // reserve contiguous run
    }
    __syncthreads();
    #pragma unroll
    for (int it = 0; it < 4; ++it) {
        if (ok[it]) {
            int pos = atomicAdd(&base[r[it] >> BSH], 1);        // LDS int cursor within run
            csr32[pos] = ((unsigned)c[it] << 16) | (unsigned)f2bf(v[it]);
            crow[pos]  = (unsigned char)(r[it] & (BROWS - 1));
        }
    }
}

// ---------------- sort: per-bucket counting sort by row, IN PLACE; emit rbeg/rcnt ----------------
__global__ __launch_bounds__(256) void sort_bucket(const int* __restrict__ gcur,
                                                   unsigned* __restrict__ csr32,
                                                   const unsigned char* __restrict__ crow,
                                                   int* __restrict__ rbeg,
                                                   int* __restrict__ rcnt, int NB) {
    __shared__ unsigned sbuf[BCAP];       // 8 KB
    __shared__ int cnt[BROWS];
    __shared__ int beg[BROWS];
    __shared__ int ofs[BROWS];
    const int t   = threadIdx.x;
    const int bkt = (int)blockIdx.x;
    int nE = gcur[bkt * 16] - bkt * BCAP;
    nE = nE < BCAP ? nE : BCAP;
    unsigned*            ce = csr32 + (size_t)bkt * BCAP;
    const unsigned char* re = crow  + (size_t)bkt * BCAP;

    if (t < BROWS) cnt[t] = 0;
    __syncthreads();
    unsigned er[8]; int rw[8];
    #pragma unroll
    for (int k = 0; k < 8; ++k) {
        int i = t + k * 256;
        if (i < nE) {
            er[k] = ce[i];
            rw[k] = (int)re[i];
            atomicAdd(&cnt[rw[k]], 1);
        } else rw[k] = -1;
    }
    __syncthreads();
    if (t < 64) {
        int c  = (t < BROWS) ? cnt[t] : 0;
        int sc = c;
        #pragma unroll
        for (int o = 1; o < 32; o <<= 1) {
            int u = __shfl_up(sc, o, 64);
            if ((t & 63) >= o) sc += u;
        }
        if (t < BROWS) { beg[t] = sc - c; ofs[t] = sc - c; }
    }
    __syncthreads();
    #pragma unroll
    for (int k = 0; k < 8; ++k) {
        if (rw[k] >= 0) {
            int pos = atomicAdd(&ofs[rw[k]], 1);
            sbuf[pos] = er[k];
        }
    }
    __syncthreads();
    #pragma unroll
    for (int k = 0; k < 8; ++k) {
        int i = t + k * 256;
        if (i < nE) ce[i] = sbuf[i];                      // sorted, coalesced write-back
    }
    if (t < BROWS) {
        rbeg[bkt * BROWS + t] = beg[t];
        rcnt[bkt * BROWS + t] = cnt[t];
    }
}

// ---------------- gather: block=(bucket, quarter); quarter pinned to 2 XCD slots ----------------
// Quarter q = packed cols {16q..16q+15} ∪ {+64} (3.2 MB slice, fits 4 MiB per-XCD L2).
// 16 lanes/edge, 4 edges per wave step, 4x4 independent chains; row descriptors in LDS.
__global__ __launch_bounds__(256) void gather_q4(const int* __restrict__ rbeg,
                                                 const int* __restrict__ rcnt,
                                                 const unsigned* __restrict__ csr32,
                                                 const unsigned* __restrict__ prebp,
                                                 const float* __restrict__ b,
                                                 float* __restrict__ out,
                                                 int M, int NB, int KHALF) {
    __shared__ int sbeg[BROWS];
    __shared__ int send[BROWS];
    const int slot = (int)blockIdx.x & 7;
    const int kk   = (int)blockIdx.x >> 3;
    const int q    = slot >> 1;
    const int bkt  = kk + (slot & 1) * KHALF;
    if (bkt >= NB) return;
    const int t = threadIdx.x, l = t & 63, w = t >> 6;
    if (t < BROWS) {
        int bg = rbeg[bkt * BROWS + t];
        sbeg[t] = bg;
        send[t] = bg + rcnt[bkt * BROWS + t];
    }
    __syncthreads();
    const int g16 = l >> 4, l16 = l & 15;
    const unsigned* sbase = csr32 + (size_t)bkt * BCAP;
    const unsigned* qbase = prebp + ((size_t)q * M) * 16 + l16;
    const float bv0 = b[q * 16 + l16];
    const float bv1 = b[q * 16 + l16 + 64];
    #pragma unroll 1
    for (int r8 = 0; r8 < 8; ++r8) {
        const int rr = w + 4 * r8;
        const int r  = (bkt << BSH) + rr;
        if (r >= M) continue;
        int j  = sbeg[rr];
        const int je = send[rr];
        float a0 = 0.f, a1 = 0.f;
        for (; j + 16 <= je; j += 16) {                  // 4x4-edge independent chains
            unsigned e0 = sbase[j + g16];
            unsigned e1 = sbase[j + 4 + g16];
            unsigned e2 = sbase[j + 8 + g16];
            unsigned e3 = sbase[j + 12 + g16];
            unsigned p0 = qbase[(size_t)(e0 >> 16) * 16];
            unsigned p1 = qbase[(size_t)(e1 >> 16) * 16];
            unsigned p2 = qbase[(size_t)(e2 >> 16) * 16];
            unsigned p3 = qbase[(size_t)(e3 >> 16) * 16];
            float v0 = __uint_as_float(e0 << 16);
            float v1 = __uint_as_float(e1 << 16);
            float v2 = __uint_as_float(e2 << 16);
            float v3 = __uint_as_float(e3 << 16);
            a0 = fmaf(v0, __uint_as_float(p0 << 16), a0);
            a1 = fmaf(v0, __uint_as_float(p0 & 0xffff0000u), a1);
            a0 = fmaf(v1, __uint_as_float(p1 << 16), a0);
            a1 = fmaf(v1, __uint_as_float(p1 & 0xffff0000u), a1);
            a0 = fmaf(v2, __uint_as_float(p2 << 16), a0);
            a1 = fmaf(v2, __uint_as_float(p2 & 0xffff0000u), a1);
            a0 = fmaf(v3, __uint_as_float(p3 << 16), a0);
            a1 = fmaf(v3, __uint_as_float(p3 & 0xffff0000u), a1);
        }
        for (; j < je; j += 4) {                         // tail, guarded (e=0 -> no-op)
            int idx = j + g16;
            unsigned e = (idx < je) ? sbase[idx] : 0u;
            unsigned p = qbase[(size_t)(e >> 16) * 16];
            float v = __uint_as_float(e << 16);
            a0 = fmaf(v, __uint_as_float(p << 16), a0);
            a1 = fmaf(v, __uint_as_float(p & 0xffff0000u), a1);
        }
        a0 += __shfl_xor(a0, 16, 64); a0 += __shfl_xor(a0, 32, 64);
        a1 += __shfl_xor(a1, 16, 64); a1 += __shfl_xor(a1, 32, 64);
        if (g16 == 0) {
            out[(size_t)r * OD + q * 16 + l16]      = fmaxf(a0 + bv0, 0.f);
            out[(size_t)r * OD + q * 16 + l16 + 64] = fmaxf(a1 + bv1, 0.f);
        }
    }
}

// ---------------- fallback (tiny ws): atomic scatter over quarter-sliced prebp ----------------
__global__ __launch_bounds__(256) void spmm_scatter(const int* __restrict__ rows,
                                                    const int* __restrict__ cols,
                                                    const float* __restrict__ vals,
                                                    const unsigned* __restrict__ prebp,
                                                    float* __restrict__ out, int E, int M) {
    const int e    = (int)((blockIdx.x * 256u + threadIdx.x) >> 6);
    const int lane = threadIdx.x & 63;
    if (e >= E) return;
    const int   r = rows[e];
    const int   c = cols[e];
    const float v = vals[e];
    const int m = lane >> 4, l16 = lane & 15;
    unsigned p = prebp[((size_t)m * M + c) * 16 + l16];
    float* o = out + (size_t)r * OD;
    unsafeAtomicAdd(o + 16 * m + l16,      v * __uint_as_float(p << 16));
    unsafeAtomicAdd(o + 16 * m + l16 + 64, v * __uint_as_float(p & 0xffff0000u));
}

__global__ __launch_bounds__(256) void bias_relu(float* __restrict__ out,
                                                 const float* __restrict__ b, int n4) {
    int i = blockIdx.x * 256 + threadIdx.x;
    if (i >= n4) return;
    float4 v = reinterpret_cast<float4*>(out)[i];
    int c = (i & ((OD / 4) - 1)) << 2;
    float4 bv = *reinterpret_cast<const float4*>(b + c);
    v.x = fmaxf(v.x + bv.x, 0.f);
    v.y = fmaxf(v.y + bv.y, 0.f);
    v.z = fmaxf(v.z + bv.z, 0.f);
    v.w = fmaxf(v.w + bv.w, 0.f);
    reinterpret_cast<float4*>(out)[i] = v;
}

extern "C" void kernel_launch(void* const* d_in, const int* in_sizes, int n_in,
                              void* d_out, int out_size, void* d_ws, size_t ws_size,
                              hipStream_t stream) {
    const float* x     = (const float*)d_in[0];
    const int*   erows = (const int*)d_in[1];
    const int*   ecols = (const int*)d_in[2];
    const float* evals = (const float*)d_in[3];
    const float* W     = (const float*)d_in[4];
    const float* b     = (const float*)d_in[5];
    float*       out   = (float*)d_out;

    const int M  = in_sizes[0] / K_DIM;          // 50000 nodes
    const int E  = in_sizes[1];                  // 1.6M edges
    const int NB = (M + BROWS - 1) >> BSH;       // 1563 buckets
    const int KHALF = (NB + 1) / 2;              // 782

    // workspace layout (16B-aligned)
    char* ws = (char*)d_ws;
    size_t off = 0;
    auto alloc = [&](size_t bytes) { char* p = ws + off; off = (off + bytes + 15) & ~(size_t)15; return p; };
    unsigned*      prebp = (unsigned*)alloc((size_t)M * 64 * sizeof(unsigned));    // 12.8 MB
    uint4*         wb    = (uint4*)alloc((size_t)8 * 8 * 64 * sizeof(uint4));      // 64 KB
    int*           gcur  = (int*)  alloc((size_t)NB * 16 * sizeof(int));           // padded cursors
    unsigned*      csr32 = (unsigned*)alloc((size_t)NB * BCAP * sizeof(unsigned)); // 12.8 MB
    unsigned char* crow  = (unsigned char*)alloc((size_t)NB * BCAP);               // 3.2 MB
    int*           rbeg  = (int*)  alloc((size_t)NB * BROWS * sizeof(int));        // 200 KB
    int*           rcnt  = (int*)  alloc((size_t)NB * BROWS * sizeof(int));        // 200 KB
    const bool bucket_ok = (off <= ws_size) && (NB <= NB_MAX) && (M <= 65536);

    const int nGemm = (M + 63) / 64;

    if (bucket_ok) {
        init_pack<<<17, 256, 0, stream>>>(W, wb, gcur, NB);
        gemm_mfma<<<nGemm, 256, 0, stream>>>(x, wb, prebp, M);
        fill_bucket<<<(E + FILL_CHUNK - 1) / FILL_CHUNK, FILL_THREADS, 0, stream>>>(
            erows, ecols, evals, gcur, csr32, crow, E, NB);
        sort_bucket<<<NB, 256, 0, stream>>>(gcur, csr32, crow, rbeg, rcnt, NB);
        gather_q4<<<8 * KHALF, 256, 0, stream>>>(rbeg, rcnt, csr32, prebp, b, out,
                                                 M, NB, KHALF);
    } else {
        init_pack<<<16, 256, 0, stream>>>(W, wb, gcur, 0);
        gemm_mfma<<<nGemm, 256, 0, stream>>>(x, wb, prebp, M);
        hipMemsetAsync(d_out, 0, (size_t)out_size * sizeof(float), stream);
        spmm_scatter<<<(E + 3) / 4, 256, 0, stream>>>(erows, ecols, evals, prebp, out, E, M);
        bias_relu<<<(out_size / 4 + 255) / 256, 256, 0, stream>>>(out, b, out_size / 4);
    }
}

// Round 14
// 120.589 us; speedup vs baseline: 1.9802x; 1.3582x over previous
//
#include <hip/hip_runtime.h>
#include <hip/hip_bf16.h>

#define K_DIM 256
#define OD 128
#define BSH 5                 // 32 rows per bucket
#define BROWS 32
#define BCAP 2048             // entries per bucket region (mean 1024, sd ~32)
#define FILL_THREADS 1024
#define FILL_CHUNK 4096       // 4 edges per thread
#define NB_MAX 2048

typedef __attribute__((ext_vector_type(8))) short short8;
typedef __attribute__((ext_vector_type(4))) float f32x4;

// pair bf16 convert (RNE) -> packed u32; compiler emits v_cvt_pk_bf16_f32
__device__ inline unsigned pack_bf2(float lo, float hi) {
    __hip_bfloat162 h = __float22bfloat162_rn(make_float2(lo, hi));
    return *reinterpret_cast<unsigned*>(&h);
}

union Frag8 { short8 s; uint4 u; };

// ---------------- init: pack W -> bf16 MFMA B-frag-linear, + bucket cursors ----------------
__global__ __launch_bounds__(256) void init_pack(const float* __restrict__ W,
                                                 uint4* __restrict__ wb,
                                                 int* __restrict__ gcur, int NB) {
    if ((int)blockIdx.x == 16) {           // bucket cursor init (padded: one per 64B line)
        for (int i = threadIdx.x; i < NB; i += 256) gcur[i * 16] = i * BCAP;
        return;
    }
    int t = blockIdx.x * 256 + threadIdx.x;
    if (t >= 8 * 8 * 64) return;
    int l  = t & 63;
    int n  = (t >> 6) & 7;
    int ks = t >> 9;
    int g  = l >> 4;
    int col = 16 * n + (l & 15);
    int kb  = 32 * ks + 4 * g;
    float e[8];
    #pragma unroll
    for (int j = 0; j < 8; ++j) {
        int k = kb + (j & 3) + 16 * (j >> 2);
        e[j] = W[(size_t)k * OD + col];
    }
    uint4 u;
    u.x = pack_bf2(e[0], e[1]);
    u.y = pack_bf2(e[2], e[3]);
    u.z = pack_bf2(e[4], e[5]);
    u.w = pack_bf2(e[6], e[7]);
    wb[t] = u;
}

// ---------------- MFMA GEMM: prebp = packed bf16(x @ W), 256 thr, no LDS, no syncs ----------------
// prebp[row*64 + w] = bf16(col w) | bf16(col w+64)<<16
__global__ __launch_bounds__(256) void gemm_mfma(const float* __restrict__ x,
                                                 const uint4* __restrict__ wb,
                                                 unsigned* __restrict__ prebp, int M) {
    const int t = threadIdx.x;
    const int l = t & 63;
    const int w = t >> 6;
    const int g = l >> 4;
    const int row  = blockIdx.x * 64 + w * 16 + (l & 15);
    const int rowc = row < M ? row : M - 1;
    const float* xp = x + (size_t)rowc * K_DIM + g * 4;

    f32x4 acc[8];
    #pragma unroll
    for (int n = 0; n < 8; ++n) acc[n] = (f32x4){0.f, 0.f, 0.f, 0.f};

    #pragma unroll
    for (int ks = 0; ks < 8; ++ks) {
        float4 xa = *reinterpret_cast<const float4*>(xp + 32 * ks);
        float4 xb = *reinterpret_cast<const float4*>(xp + 32 * ks + 16);
        Frag8 a;
        a.u.x = pack_bf2(xa.x, xa.y);
        a.u.y = pack_bf2(xa.z, xa.w);
        a.u.z = pack_bf2(xb.x, xb.y);
        a.u.w = pack_bf2(xb.z, xb.w);
        const uint4* wp = wb + (size_t)ks * 8 * 64 + l;
        #pragma unroll
        for (int n = 0; n < 8; ++n) {
            Frag8 bfrag;
            bfrag.u = wp[n * 64];
            acc[n] = __builtin_amdgcn_mfma_f32_16x16x32_bf16(a.s, bfrag.s, acc[n], 0, 0, 0);
        }
    }
    const int rbase = blockIdx.x * 64 + w * 16 + g * 4;
    #pragma unroll
    for (int r = 0; r < 4; ++r) {
        int ro = rbase + r;
        if (ro < M) {
            unsigned* dst = prebp + (size_t)ro * 64 + (l & 15);
            #pragma unroll
            for (int m = 0; m < 4; ++m)
                dst[16 * m] = pack_bf2(acc[m][r], acc[m + 4][r]);
        }
    }
}

// ---------------- fill: bucket-grouped edge list, block-chunked reservation ----------------
// 1024 threads, 4 edges/thread held in registers across both passes.
// entry.x = (row&31)<<16 | col, entry.y = val bits. Bucket b region: csr[b*BCAP ...).
__global__ __launch_bounds__(1024) void fill_bucket(const int* __restrict__ rows,
                                                    const int* __restrict__ cols,
                                                    const float* __restrict__ vals,
                                                    int* __restrict__ gcur,
                                                    uint2* __restrict__ csr, int E, int NB) {
    __shared__ int cnt[NB_MAX];
    __shared__ int base[NB_MAX];
    const int t  = threadIdx.x;
    const int e0 = blockIdx.x * FILL_CHUNK;
    for (int i = t; i < NB; i += FILL_THREADS) cnt[i] = 0;
    __syncthreads();
    int  r[4]; int c[4]; float v[4]; bool ok[4];
    #pragma unroll
    for (int it = 0; it < 4; ++it) {
        int i = e0 + it * FILL_THREADS + t;
        ok[it] = (i < E);
        if (ok[it]) {
            r[it] = rows[i];
            c[it] = cols[i];
            v[it] = vals[i];
            atomicAdd(&cnt[r[it] >> BSH], 1);
        }
    }
    __syncthreads();
    for (int bkt = t; bkt < NB; bkt += FILL_THREADS) {
        int cn = cnt[bkt];
        base[bkt] = cn ? atomicAdd(&gcur[bkt * 16], cn) : 0;   // reserve contiguous run
    }
    __syncthreads();
    #pragma unroll
    for (int it = 0; it < 4; ++it) {
        if (ok[it]) {
            int pos = atomicAdd(&base[r[it] >> BSH], 1);        // LDS int cursor within run
            csr[pos] = make_uint2(((unsigned)(r[it] & (BROWS - 1)) << 16) | (unsigned)c[it],
                                  __float_as_uint(v[it]));
        }
    }
}

// ---------------- gather: 512 thr/bucket; reg-staged counting sort; register accumulation ----------------
// Wave w gathers rows {w, w+8, w+16, w+24}; lane l owns cols {l, l+64}.
__global__ __launch_bounds__(512) void gather_sort(const int* __restrict__ gcur,
                                                   const uint2* __restrict__ csr,
                                                   const unsigned* __restrict__ prebp,
                                                   const float* __restrict__ b,
                                                   float* __restrict__ out, int M) {
    __shared__ uint2 sbuf[BCAP];          // row-sorted entries, 16 KB
    __shared__ int cnt[BROWS];
    __shared__ int beg[BROWS];
    __shared__ int ofs[BROWS];
    const int t   = threadIdx.x;
    const int bkt = (int)blockIdx.x;
    int nE = gcur[bkt * 16] - bkt * BCAP;
    nE = nE < BCAP ? nE : BCAP;
    const uint2* ep = csr + (size_t)bkt * BCAP;

    if (t < BROWS) cnt[t] = 0;
    __syncthreads();
    // pass 1: register-stage entries + count rows (native LDS int atomics)
    uint2 er[4];
    #pragma unroll
    for (int k = 0; k < 4; ++k) {
        int i = t + k * 512;
        if (i < nE) {
            er[k] = ep[i];
            atomicAdd(&cnt[er[k].x >> 16], 1);
        } else er[k].x = 0xffffffffu;
    }
    __syncthreads();
    // exclusive scan of 32 counts in wave 0
    if (t < 64) {
        int c  = (t < BROWS) ? cnt[t] : 0;
        int sc = c;
        #pragma unroll
        for (int o = 1; o < 32; o <<= 1) {
            int u = __shfl_up(sc, o, 64);
            if ((t & 63) >= o) sc += u;
        }
        if (t < BROWS) { beg[t] = sc - c; ofs[t] = sc - c; }
    }
    __syncthreads();
    // pass 2: scatter regs into row-sorted LDS buffer
    #pragma unroll
    for (int k = 0; k < 4; ++k) {
        if (er[k].x != 0xffffffffu) {
            int r   = (int)(er[k].x >> 16);
            int pos = atomicAdd(&ofs[r], 1);
            sbuf[pos] = make_uint2(er[k].x & 0xffffu, er[k].y);
        }
    }
    __syncthreads();

    // per-wave register gather over 4 rows (stride 8)
    const int l = t & 63, w = t >> 6;
    const float bv0 = b[l], bv1 = b[64 + l];
    const unsigned* pl = prebp + l;
    #pragma unroll 1
    for (int q = 0; q < 4; ++q) {
        int rr = w + 8 * q;
        int r  = (bkt << BSH) + rr;
        if (r >= M) continue;
        int j  = beg[rr];
        int je = j + cnt[rr];
        float a0 = 0.f, a1 = 0.f;
        for (; j + 7 < je; j += 8) {                     // 8 independent chains
            uint2 e0 = sbuf[j],     e1 = sbuf[j + 1], e2 = sbuf[j + 2], e3 = sbuf[j + 3];
            uint2 e4 = sbuf[j + 4], e5 = sbuf[j + 5], e6 = sbuf[j + 6], e7 = sbuf[j + 7];
            unsigned p0 = pl[(size_t)e0.x * 64];
            unsigned p1 = pl[(size_t)e1.x * 64];
            unsigned p2 = pl[(size_t)e2.x * 64];
            unsigned p3 = pl[(size_t)e3.x * 64];
            unsigned p4 = pl[(size_t)e4.x * 64];
            unsigned p5 = pl[(size_t)e5.x * 64];
            unsigned p6 = pl[(size_t)e6.x * 64];
            unsigned p7 = pl[(size_t)e7.x * 64];
            float v0 = __uint_as_float(e0.y), v1 = __uint_as_float(e1.y);
            float v2 = __uint_as_float(e2.y), v3 = __uint_as_float(e3.y);
            float v4 = __uint_as_float(e4.y), v5 = __uint_as_float(e5.y);
            float v6 = __uint_as_float(e6.y), v7 = __uint_as_float(e7.y);
            a0 = fmaf(v0, __uint_as_float(p0 << 16), a0);
            a1 = fmaf(v0, __uint_as_float(p0 & 0xffff0000u), a1);
            a0 = fmaf(v1, __uint_as_float(p1 << 16), a0);
            a1 = fmaf(v1, __uint_as_float(p1 & 0xffff0000u), a1);
            a0 = fmaf(v2, __uint_as_float(p2 << 16), a0);
            a1 = fmaf(v2, __uint_as_float(p2 & 0xffff0000u), a1);
            a0 = fmaf(v3, __uint_as_float(p3 << 16), a0);
            a1 = fmaf(v3, __uint_as_float(p3 & 0xffff0000u), a1);
            a0 = fmaf(v4, __uint_as_float(p4 << 16), a0);
            a1 = fmaf(v4, __uint_as_float(p4 & 0xffff0000u), a1);
            a0 = fmaf(v5, __uint_as_float(p5 << 16), a0);
            a1 = fmaf(v5, __uint_as_float(p5 & 0xffff0000u), a1);
            a0 = fmaf(v6, __uint_as_float(p6 << 16), a0);
            a1 = fmaf(v6, __uint_as_float(p6 & 0xffff0000u), a1);
            a0 = fmaf(v7, __uint_as_float(p7 << 16), a0);
            a1 = fmaf(v7, __uint_as_float(p7 & 0xffff0000u), a1);
        }
        for (; j < je; ++j) {
            uint2 e = sbuf[j];
            unsigned p = pl[(size_t)e.x * 64];
            float v = __uint_as_float(e.y);
            a0 = fmaf(v, __uint_as_float(p << 16), a0);
            a1 = fmaf(v, __uint_as_float(p & 0xffff0000u), a1);
        }
        out[(size_t)r * OD + l]      = fmaxf(a0 + bv0, 0.f);
        out[(size_t)r * OD + 64 + l] = fmaxf(a1 + bv1, 0.f);
    }
}

// ---------------- fallback (tiny ws): atomic scatter over packed bf16 pre ----------------
__global__ __launch_bounds__(256) void spmm_scatter(const int* __restrict__ rows,
                                                    const int* __restrict__ cols,
                                                    const float* __restrict__ vals,
                                                    const unsigned* __restrict__ prebp,
                                                    float* __restrict__ out, int E) {
    const int e    = (int)((blockIdx.x * 256u + threadIdx.x) >> 6);
    const int lane = threadIdx.x & 63;
    if (e >= E) return;
    const int   r = rows[e];
    const int   c = cols[e];
    const float v = vals[e];
    unsigned p = prebp[(size_t)c * 64 + lane];
    float* o = out + (size_t)r * OD;
    unsafeAtomicAdd(o + lane,      v * __uint_as_float(p << 16));
    unsafeAtomicAdd(o + lane + 64, v * __uint_as_float(p & 0xffff0000u));
}

__global__ __launch_bounds__(256) void bias_relu(float* __restrict__ out,
                                                 const float* __restrict__ b, int n4) {
    int i = blockIdx.x * 256 + threadIdx.x;
    if (i >= n4) return;
    float4 v = reinterpret_cast<float4*>(out)[i];
    int c = (i & ((OD / 4) - 1)) << 2;
    float4 bv = *reinterpret_cast<const float4*>(b + c);
    v.x = fmaxf(v.x + bv.x, 0.f);
    v.y = fmaxf(v.y + bv.y, 0.f);
    v.z = fmaxf(v.z + bv.z, 0.f);
    v.w = fmaxf(v.w + bv.w, 0.f);
    reinterpret_cast<float4*>(out)[i] = v;
}

extern "C" void kernel_launch(void* const* d_in, const int* in_sizes, int n_in,
                              void* d_out, int out_size, void* d_ws, size_t ws_size,
                              hipStream_t stream) {
    const float* x     = (const float*)d_in[0];
    const int*   erows = (const int*)d_in[1];
    const int*   ecols = (const int*)d_in[2];
    const float* evals = (const float*)d_in[3];
    const float* W     = (const float*)d_in[4];
    const float* b     = (const float*)d_in[5];
    float*       out   = (float*)d_out;

    const int M  = in_sizes[0] / K_DIM;          // 50000 nodes
    const int E  = in_sizes[1];                  // 1.6M edges
    const int NB = (M + BROWS - 1) >> BSH;       // 1563 buckets

    // workspace layout (16B-aligned)
    char* ws = (char*)d_ws;
    size_t off = 0;
    auto alloc = [&](size_t bytes) { char* p = ws + off; off = (off + bytes + 15) & ~(size_t)15; return p; };
    unsigned* prebp = (unsigned*)alloc((size_t)M * 64 * sizeof(unsigned));        // 12.8 MB
    uint4*    wb    = (uint4*)alloc((size_t)8 * 8 * 64 * sizeof(uint4));          // 64 KB
    int*      gcur  = (int*)  alloc((size_t)NB * 16 * sizeof(int));               // padded cursors
    uint2*    csr   = (uint2*)alloc((size_t)NB * BCAP * sizeof(uint2));           // 25.6 MB
    const bool bucket_ok = (off <= ws_size) && (NB <= NB_MAX) && (M <= 65536);

    const int nGemm = (M + 63) / 64;

    if (bucket_ok) {
        init_pack<<<17, 256, 0, stream>>>(W, wb, gcur, NB);
        gemm_mfma<<<nGemm, 256, 0, stream>>>(x, wb, prebp, M);
        fill_bucket<<<(E + FILL_CHUNK - 1) / FILL_CHUNK, FILL_THREADS, 0, stream>>>(
            erows, ecols, evals, gcur, csr, E, NB);
        gather_sort<<<NB, 512, 0, stream>>>(gcur, csr, prebp, b, out, M);
    } else {
        init_pack<<<16, 256, 0, stream>>>(W, wb, gcur, 0);
        gemm_mfma<<<nGemm, 256, 0, stream>>>(x, wb, prebp, M);
        hipMemsetAsync(d_out, 0, (size_t)out_size * sizeof(float), stream);
        spmm_scatter<<<(E + 3) / 4, 256, 0, stream>>>(erows, ecols, evals, prebp, out, E);
        bias_relu<<<(out_size / 4 + 255) / 256, 256, 0, stream>>>(out, b, out_size / 4);
    }
}